// Round 6
// baseline (181.304 us; speedup 1.0000x reference)
//
#include <hip/hip_runtime.h>

// MaskedContrastiveLoss: loss = 0.5*[mean_i(rowLSE_i - pos_i) + mean_j(colLSE_j - pos_j)]
// logits = (A @ B^T) * (1/0.07), A,B: [256, 65536] fp32 L2-normalized rows.
//
// R6: the R1/R5 plateau (38% HBM) is load serialization: the compiler sinks
// VGPR-staged prefetch loads to their LDS stores (VGPR_Count=128 both rounds),
// costing a full HBM latency per load. Fix: global_load_lds async DMA (no dest
// VGPR -> nothing to sink), wave-PRIVATE double-buffered LDS tiles (64x32 fp32
// A+B per wave, 128 KB/block, 1 block/CU), NO __syncthreads anywhere in the
// K-loop (the m97 vmcnt(0)-drain trap), manual s_waitcnt vmcnt(16) via inline
// asm for the 1-ahead pipeline. fp32 lives in LDS; bf16 conversion happens at
// fragment read. DMA's LDS mapping is fixed (base + lane*16), so bank
// conflicts are broken by XOR-swizzling the 16B chunk index on the GLOBAL
// address side: LDS[row][slot] = global chunk slot^(row&7) -> fragment reads
// hit 8 distinct bank quartets, 2 lanes each (2-way = free).

#define D_DIM 65536
#define B_DIM 256
#define C_CHUNKS 64
#define KC (D_DIM / C_CHUNKS)  // 1024 k per chunk
#define BK 32                  // one 16x16x32 MFMA K-step per stage
#define NST (KC / BK)          // 32 stages

constexpr float TEMP = 1.0f / 0.07f;

typedef short short8 __attribute__((ext_vector_type(8)));
typedef float floatx4 __attribute__((ext_vector_type(4)));

typedef __attribute__((address_space(3))) unsigned lds_u32;
typedef __attribute__((address_space(1))) const unsigned glb_u32;

__device__ __forceinline__ void dma16(const float* g, float* l) {
  // lane i of the wave writes 16 B at (wave-uniform l) + i*16
  __builtin_amdgcn_global_load_lds((glb_u32*)g, (lds_u32*)l, 16, 0, 0);
}

#define WAITCNT_VM16() asm volatile("s_waitcnt vmcnt(16)" ::: "memory")
#define WAITCNT_VM0() asm volatile("s_waitcnt vmcnt(0)" ::: "memory")

__device__ __forceinline__ unsigned fbits(float f) { return __builtin_bit_cast(unsigned, f); }

// two f32 -> packed bf16 (round-to-nearest, ties-up): 2 adds + 1 v_perm
__device__ __forceinline__ unsigned pkbf(float lo, float hi) {
  return __builtin_amdgcn_perm(fbits(hi) + 0x8000u, fbits(lo) + 0x8000u, 0x07060302);
}

__device__ __forceinline__ short8 cvt_frag(float4 lo, float4 hi) {
  union { unsigned u[4]; short8 s; } r;
  r.u[0] = pkbf(lo.x, lo.y);
  r.u[1] = pkbf(lo.z, lo.w);
  r.u[2] = pkbf(hi.x, hi.y);
  r.u[3] = pkbf(hi.z, hi.w);
  return r.s;
}

// grid = 4 tiles * 64 chunks = 256 blocks (1/CU), 256 threads (4 waves).
// bid = chunk*4 + tile: blocks sharing a chunk are CONSECUTIVE (R1-proven
// compulsory fetch). Wave owns a 64x64 quadrant, full chunk K, private LDS.
__global__ __launch_bounds__(256, 1) void gemm_splitk(
    const float* __restrict__ A, const float* __restrict__ Bm,
    float* __restrict__ partials, float* __restrict__ colsum,
    float* __restrict__ out, unsigned* __restrict__ counter) {
  __shared__ float lds[4][2][2][64][BK];  // [wave][buf][A/B][row][k] = 128 KB

  const int bid = blockIdx.x;
  const int t = threadIdx.x;
  if (bid == 0) {  // zero reduce accumulators (ws/out are poisoned each launch)
    colsum[t] = 0.f;
    if (t == 0) { *out = 0.f; *counter = 0u; }
  }

  const int chunk = bid >> 2;
  const int tile = bid & 3;
  const int mt = (tile & 1) * 128;
  const int nt = (tile >> 1) * 128;

  const int lane = t & 63;
  const int w = t >> 6;
  const int wm = mt + (w & 1) * 64;  // wave's 64 A-rows
  const int wn = nt + (w >> 1) * 64; // wave's 64 B-rows
  const int r16 = lane & 15;
  const int q = lane >> 4;
  const int sw = r16 & 7;  // fragment-read swizzle key

  const size_t k0 = (size_t)chunk * KC;

  // DMA staging: one instr = 8 rows x 128 B. lane -> row lane>>3, slot lane&7;
  // global chunk fetched = slot ^ (row&7)  (row&7 == (lane>>3)&7 for all j).
  const int lr = lane >> 3;
  const int gchunk = (lane & 7) ^ (lr & 7);
  const float* Ab = A + (size_t)(wm + lr) * D_DIM + k0 + gchunk * 4;
  const float* Bb = Bm + (size_t)(wn + lr) * D_DIM + k0 + gchunk * 4;

  float* L = &lds[w][0][0][0][0];  // buf stride 4096 floats, mat stride 2048

  floatx4 acc[16];
#pragma unroll
  for (int i = 0; i < 16; ++i) acc[i] = (floatx4)0.f;

#define ISSUE(buf, s)                                                       \
  {                                                                         \
    const float* ga = Ab + (size_t)(s) * BK;                                \
    const float* gb = Bb + (size_t)(s) * BK;                                \
    float* la = L + (buf) * 4096;                                           \
    float* lb = la + 2048;                                                  \
    _Pragma("unroll") for (int j = 0; j < 8; ++j)                           \
        dma16(ga + (size_t)j * 8 * D_DIM, la + j * 8 * BK);                 \
    _Pragma("unroll") for (int j = 0; j < 8; ++j)                           \
        dma16(gb + (size_t)j * 8 * D_DIM, lb + j * 8 * BK);                 \
  }

#define COMPUTE(buf)                                                        \
  {                                                                         \
    const float* la = L + (buf) * 4096;                                     \
    const float* lb = la + 2048;                                            \
    short8 af[4], bf[4];                                                    \
    const int s0 = (2 * q) ^ sw, s1 = (2 * q + 1) ^ sw;                     \
    _Pragma("unroll") for (int mb = 0; mb < 4; ++mb) {                      \
      const float* rp = la + (mb * 16 + r16) * BK;                          \
      af[mb] = cvt_frag(*(const float4*)(rp + s0 * 4),                      \
                        *(const float4*)(rp + s1 * 4));                     \
    }                                                                       \
    _Pragma("unroll") for (int nb = 0; nb < 4; ++nb) {                      \
      const float* rp = lb + (nb * 16 + r16) * BK;                          \
      bf[nb] = cvt_frag(*(const float4*)(rp + s0 * 4),                      \
                        *(const float4*)(rp + s1 * 4));                     \
    }                                                                       \
    _Pragma("unroll") for (int mb = 0; mb < 4; ++mb)                        \
        _Pragma("unroll") for (int nb = 0; nb < 4; ++nb)                    \
            acc[mb * 4 + nb] = __builtin_amdgcn_mfma_f32_16x16x32_bf16(     \
                af[mb], bf[nb], acc[mb * 4 + nb], 0, 0, 0);                 \
  }

  ISSUE(0, 0)
  ISSUE(1, 1)
#pragma unroll 1
  for (int s = 0; s + 2 < NST; s += 2) {
    WAITCNT_VM16();  // 16 newest (next stage) may be outstanding; this buf done
    COMPUTE(0)
    ISSUE(0, s + 2)
    WAITCNT_VM16();
    COMPUTE(1)
    ISSUE(1, s + 3)
  }
  WAITCNT_VM16();
  COMPUTE(0)  // stage NST-2
  WAITCNT_VM0();
  COMPUTE(1)  // stage NST-1
#undef ISSUE
#undef COMPUTE

  // epilogue: C/D layout col = lane&15, row = q*4 + r (per 16x16 block)
  float* op = partials + (size_t)chunk * (B_DIM * B_DIM);
#pragma unroll
  for (int mb = 0; mb < 4; ++mb) {
    const int gi0 = wm + mb * 16 + q * 4;
#pragma unroll
    for (int nb = 0; nb < 4; ++nb) {
      const int gj = wn + nb * 16 + r16;
#pragma unroll
      for (int r = 0; r < 4; ++r)
        op[(size_t)(gi0 + r) * B_DIM + gj] = acc[mb * 4 + nb][r];
    }
  }
}

// block i: sum chunks for row i (coalesced), rowLSE_i + pos_i -> out;
// exp values atomicAdd into colsum[j]; last block finishes the column LSEs.
__global__ __launch_bounds__(256, 2) void reduce_all(
    const float* __restrict__ partials, float* __restrict__ colsum,
    float* __restrict__ out, unsigned* __restrict__ counter) {
  const int i = blockIdx.x;
  const int j = threadIdx.x;

  float s = 0.f;
  const float* p = partials + (size_t)i * B_DIM + j;
#pragma unroll 8
  for (int c = 0; c < C_CHUNKS; ++c) s += p[(size_t)c * (B_DIM * B_DIM)];
  const float lg = s * TEMP;

  __shared__ float posv;
  if (j == i) posv = lg;

  // |logit| <= TEMP (Cauchy-Schwarz, unit rows): exp safe without max-shift
  const float e = expf(lg);
  atomicAdd(&colsum[j], e);

  float r = e;
#pragma unroll
  for (int off = 32; off > 0; off >>= 1) r += __shfl_down(r, off);
  __shared__ float wsum[4];
  if ((j & 63) == 0) wsum[j >> 6] = r;
  __threadfence();  // publish colsum adds before counter increment
  __syncthreads();

  __shared__ bool last;
  if (j == 0) {
    const float rowsum = wsum[0] + wsum[1] + wsum[2] + wsum[3];
    atomicAdd(out, (logf(rowsum) - 2.f * posv) * (0.5f / 256.f));
    last = (atomicAdd(counter, 1u) == B_DIM - 1);
  }
  __syncthreads();

  if (last) {
    __threadfence();  // acquire: all blocks' colsum adds visible
    float cl = logf(colsum[j]);
#pragma unroll
    for (int off = 32; off > 0; off >>= 1) cl += __shfl_down(cl, off);
    if ((j & 63) == 0) wsum[j >> 6] = cl;
    __syncthreads();
    if (j == 0)
      atomicAdd(out, (wsum[0] + wsum[1] + wsum[2] + wsum[3]) * (0.5f / 256.f));
  }
}

extern "C" void kernel_launch(void* const* d_in, const int* in_sizes, int n_in,
                              void* d_out, int out_size, void* d_ws, size_t ws_size,
                              hipStream_t stream) {
  (void)in_sizes; (void)n_in; (void)out_size; (void)ws_size;
  const float* A = (const float*)d_in[0];
  const float* Bm = (const float*)d_in[1];
  float* out = (float*)d_out;

  // ws: [partials: 64*256*256 f32 = 16 MB][colsum: 256 f32][counter: 1 u32]
  float* partials = (float*)d_ws;
  float* colsum = partials + (size_t)C_CHUNKS * B_DIM * B_DIM;
  unsigned* counter = (unsigned*)(colsum + B_DIM);

  gemm_splitk<<<4 * C_CHUNKS, 256, 0, stream>>>(A, Bm, partials, colsum, out, counter);
  reduce_all<<<B_DIM, B_DIM, 0, stream>>>(partials, colsum, out, counter);
}